// Round 16
// baseline (1756.922 us; speedup 1.0000x reference)
//
#include <hip/hip_runtime.h>
#include <stdint.h>

// Echo-state recurrence h' = 0.8h + 0.2*tanh([h|x_t] @ [W;W_in]), out[b,t,:]=h'.
// Persistent kernel, 8 domains x 32 WGs; WG = 4 batches x 32 cols; W/W_in in VGPRs
// as MFMA B-frags (f16). Sync: tag-in-data u32 (f16<<16|step); publish via
// compiler-emitted relaxed agent-scope atomic stores; poll: asm dwordx4 sc1
// + in-asm vmcnt(0), s_sleep(1)-throttled. hl is wave-private (poll slice ==
// MFMA read slice) -> ordered by lgkmcnt fence, no barrier (R15).
// R16: finalize DISTRIBUTED across all 8 waves (each wave: 4 cols x 4 batches,
// 1 tanh/lane, publish-first) + part4 double-buffered by t&1 -> barrier E
// removed. ONE barrier per step (C). Audit: t+1 part4 writes hit buffer
// (t+1)&1; t+2 writes to t&1 sit behind barrier C(t+1) which finalizers only
// reach after their t-reads.

#define T_   1024
#define D_   256
#define U_   1024
#define NTHR 512
#define HROW 1040        // shorts per h row: 1024 + 16 pad
#define BAIL (1u << 20)

typedef _Float16     f16x8 __attribute__((ext_vector_type(8)));
typedef float        f32x4 __attribute__((ext_vector_type(4)));
typedef unsigned int u32x4 __attribute__((ext_vector_type(4)));

#if defined(__has_builtin) && __has_builtin(__builtin_amdgcn_rcpf)
__device__ __forceinline__ float rcp_fast(float v) { return __builtin_amdgcn_rcpf(v); }
#else
__device__ __forceinline__ float rcp_fast(float v) { return 1.f / v; }
#endif

__device__ __forceinline__ float tanh_fast(float v) {
    float e = __expf(2.f * v);
    return 1.f - 2.f * rcp_fast(e + 1.f);   // ~1e-6 abs err, exact at +-inf
}

__device__ __forceinline__ unsigned f2u16(_Float16 v) {
    return (unsigned)__builtin_bit_cast(unsigned short, v);
}

// LDS-ordered raw barrier: ds ops retired, then barrier; vmem stays in flight.
__device__ __forceinline__ void lds_barrier() {
    asm volatile("s_waitcnt lgkmcnt(0)" ::: "memory");
    __builtin_amdgcn_sched_barrier(0);
    __builtin_amdgcn_s_barrier();
}

// Wave-local ordering fence: ds writes retired before following ds reads issue.
__device__ __forceinline__ void lds_fence() {
    asm volatile("s_waitcnt lgkmcnt(0)" ::: "memory");
    __builtin_amdgcn_sched_barrier(0);
}

__global__ __launch_bounds__(NTHR, 2) void k_recur(const float* __restrict__ x,
                                                   const float* __restrict__ W,
                                                   const float* __restrict__ win,
                                                   float* __restrict__ out,
                                                   u32x4* __restrict__ hc) {
    __shared__ short hl16[4 * HROW];     // [4 b][1024 h + pad] f16
    __shared__ f32x4 part4[2][256];      // dbuf [8 wave][32 col] -> (b0..b3)
    unsigned int* hl32  = (unsigned int*)hl16;
    float*        partf = (float*)part4;
    unsigned int* hc32  = (unsigned int*)hc;

    const int tid  = threadIdx.x;
    const int dom  = blockIdx.x & 7;
    const int wg   = blockIdx.x >> 3;
    const int c0   = wg * 32;
    const int b0   = dom * 4;
    const int lane = tid & 63;
    const int wv   = tid >> 6;          // wave owns h-cols [wv*128,+128) + x-cols [wv*32,+32)
    const int l15  = lane & 15;
    const int lg   = lane >> 4;         // 0..3

    // ---- one-time: W / W_in -> register B-fragments (f16) ----
    f16x8 bw[5][2];
#pragma unroll
    for (int kt = 0; kt < 4; ++kt)
#pragma unroll
        for (int ct = 0; ct < 2; ++ct)
#pragma unroll
            for (int j = 0; j < 8; ++j)
                bw[kt][ct][j] =
                    (_Float16)W[(size_t)(wv * 128 + kt * 32 + lg * 8 + j) * U_ + c0 + ct * 16 + l15];
#pragma unroll
    for (int ct = 0; ct < 2; ++ct)
#pragma unroll
        for (int j = 0; j < 8; ++j)
            bw[4][ct][j] =
                (_Float16)win[(size_t)(wv * 32 + lg * 8 + j) * U_ + c0 + ct * 16 + l15];

    // zero h region (h must be 0 at t=0)
    for (int i = tid; i < 2 * HROW; i += NTHR) hl32[i] = 0;
    __syncthreads();   // one-time, cold

    // A-frag base: row = batch (l15&3), k-group = lg
    const int ab = (l15 & 3) * HROW + lg * 8;
    // x source for this lane's kt=4 A-fragment: batch l15&3, cols wv*32 + lg*8 ..+8
    const float* xg = &x[((size_t)(b0 + (l15 & 3)) * T_) * D_ + wv * 32 + lg * 8];

    // prologue: x[t=0] into regs
    float4 xa = *(const float4*)xg;
    float4 xc = *(const float4*)(xg + 4);
    xg += D_;

    // finalize ownership (lanes 0..15 of each wave): col = wv*4 + (l>>2), batch = l&3
    const int fcol = wv * 4 + (l15 >> 2);
    const int fbat = lane & 3;
    float hs = 0.f;                     // per-(col,batch) state

    for (int t = 0; t < T_; ++t) {
        u32x4 va, vb;
        if (t > 0) {
            // ---- poll own wave slice: 2 cols/thread, all 8 tags == t ----
            const u32x4* pp = hc + (size_t)((t & 1) * 8192 + dom * 1024 + 2 * tid);
            unsigned spin = 0;
            int ok;
            for (;;) {
                asm volatile(
                    "global_load_dwordx4 %0, %2, off sc1\n\t"
                    "global_load_dwordx4 %1, %2, off offset:16 sc1\n\t"
                    "s_waitcnt vmcnt(0)"
                    : "=&v"(va), "=&v"(vb)
                    : "v"(pp) : "memory");
                unsigned tg = (unsigned)t;
                ok = ((va[0] & 0xffffu) == tg) & ((va[1] & 0xffffu) == tg) &
                     ((va[2] & 0xffffu) == tg) & ((va[3] & 0xffffu) == tg) &
                     ((vb[0] & 0xffffu) == tg) & ((vb[1] & 0xffffu) == tg) &
                     ((vb[2] & 0xffffu) == tg) & ((vb[3] & 0xffffu) == tg);
                if (__all(ok) || ++spin > BAIL) break;
                __builtin_amdgcn_s_sleep(1);   // ~64 cyc: decongest the fabric
            }
            // ---- write polled h (cols 2*tid, 2*tid+1 per batch; wave-private) ----
#pragma unroll
            for (int b = 0; b < 4; ++b)
                hl32[b * (HROW / 2) + tid] = (va[b] >> 16) | (vb[b] & 0xffff0000u);
        }

        // ---- convert x[t] (loaded last iteration) to f16 ----
        f16x8 xf;
        xf[0] = (_Float16)xa.x; xf[1] = (_Float16)xa.y;
        xf[2] = (_Float16)xa.z; xf[3] = (_Float16)xa.w;
        xf[4] = (_Float16)xc.x; xf[5] = (_Float16)xc.y;
        xf[6] = (_Float16)xc.z; xf[7] = (_Float16)xc.w;

        lds_fence();   // wave-local: hl writes retired before A-frag reads

        // ---- load x[t+1]: completion tracked at next iteration's use ----
        if (t + 1 < T_) {
            xa = *(const float4*)xg;
            xc = *(const float4*)(xg + 4);
            xg += D_;
        }

        // ---- MFMA: A = [h (own LDS slice) | x (regs)], B in regs, K=160 ----
        f32x4 acc0 = {0.f, 0.f, 0.f, 0.f}, acc1 = {0.f, 0.f, 0.f, 0.f};
#pragma unroll
        for (int kt = 0; kt < 4; ++kt) {
            f16x8 av = *reinterpret_cast<const f16x8*>(&hl16[ab + wv * 128 + kt * 32]);
            acc0 = __builtin_amdgcn_mfma_f32_16x16x32_f16(av, bw[kt][0], acc0, 0, 0, 0);
            acc1 = __builtin_amdgcn_mfma_f32_16x16x32_f16(av, bw[kt][1], acc1, 0, 0, 0);
        }
        acc0 = __builtin_amdgcn_mfma_f32_16x16x32_f16(xf, bw[4][0], acc0, 0, 0, 0);
        acc1 = __builtin_amdgcn_mfma_f32_16x16x32_f16(xf, bw[4][1], acc1, 0, 0, 0);

        if (lane < 16) {
            part4[t & 1][wv * 32 + l15]      = acc0;
            part4[t & 1][wv * 32 + 16 + l15] = acc1;
        }
        lds_barrier();   // (C) the ONLY per-step barrier: partials ready

        // ---- distributed finalize: each wave, lanes 0..15 own (fcol, fbat) ----
        if (lane < 16) {
            float s = 0.f;
#pragma unroll
            for (int w2 = 0; w2 < 8; ++w2)
                s += partf[(t & 1) * 1024 + (w2 * 32 + fcol) * 4 + fbat];
            float hn = 0.8f * hs + 0.2f * tanh_fast(s);
            hs = hn;
            // publish FIRST (critical edge): u32 self-tagged
            unsigned pk = (f2u16((_Float16)hn) << 16) | ((unsigned)(t + 1) & 0xffffu);
            __hip_atomic_store(
                &hc32[(size_t)(((t + 1) & 1) * 32768 + dom * 4096 + (c0 + fcol) * 4 + fbat)],
                pk, __ATOMIC_RELAXED, __HIP_MEMORY_SCOPE_AGENT);
            // out store (fire-and-forget)
            out[((size_t)(b0 + fbat) * T_ + t) * U_ + c0 + fcol] = hn;
        }
        // no barrier E: part4 double-buffered; next same-buffer write is behind C(t+1)
    }
}

extern "C" void kernel_launch(void* const* d_in, const int* in_sizes, int n_in,
                              void* d_out, int out_size, void* d_ws, size_t ws_size,
                              hipStream_t stream) {
    const float* x   = (const float*)d_in[0];   // [32,1024,256]
    const float* W   = (const float*)d_in[1];   // [1024,1024]
    const float* win = (const float*)d_in[2];   // [256,1024]
    float* out = (float*)d_out;                 // [32,1024,1024]

    // ws: hcast ring = 2 slots x 8 dom x 1024 cols x 16 B = 256 KB
    u32x4* hc = (u32x4*)d_ws;
    if (ws_size < 2 * 8 * 1024 * 16) return;

    hipMemsetAsync(d_ws, 0, 2 * 8 * 1024 * 16, stream);   // clean tags every call
    k_recur<<<dim3(256), dim3(NTHR), 0, stream>>>(x, W, win, out, hc);
}

// Round 17
// 1428.454 us; speedup vs baseline: 1.2299x; 1.2299x over previous
//
#include <hip/hip_runtime.h>
#include <stdint.h>

// Echo-state recurrence h' = 0.8h + 0.2*tanh([h|x_t] @ [W;W_in]), out[b,t,:]=h'.
// Persistent kernel, 8 domains x 32 WGs; WG = 4 batches x 32 cols; W/W_in in VGPRs
// as MFMA B-frags (f16). Sync: tag-in-data u32 (f16<<16|step); publish via
// compiler-emitted relaxed agent-scope u64 atomic stores; poll: asm dwordx4 sc1
// + in-asm vmcnt(0), s_sleep(1)-throttled. hl is wave-private (poll slice ==
// MFMA read slice) -> ordered by lgkmcnt fence, no barrier. Single-wave
// finalize + barriers C/E retained (R16 showed distributing finalize and
// dropping E regresses 23% via producer-wave fan-in + unpaced poll flood).
// == R15 verbatim (best verified: 1429 us, absmax 0.0039). ==

#define T_   1024
#define D_   256
#define U_   1024
#define NTHR 512
#define HROW 1040        // shorts per h row: 1024 + 16 pad
#define BAIL (1u << 20)

typedef _Float16     f16x8 __attribute__((ext_vector_type(8)));
typedef float        f32x4 __attribute__((ext_vector_type(4)));
typedef unsigned int u32x4 __attribute__((ext_vector_type(4)));

#if defined(__has_builtin) && __has_builtin(__builtin_amdgcn_rcpf)
__device__ __forceinline__ float rcp_fast(float v) { return __builtin_amdgcn_rcpf(v); }
#else
__device__ __forceinline__ float rcp_fast(float v) { return 1.f / v; }
#endif

__device__ __forceinline__ float tanh_fast(float v) {
    float e = __expf(2.f * v);
    return 1.f - 2.f * rcp_fast(e + 1.f);   // ~1e-6 abs err, exact at +-inf
}

__device__ __forceinline__ unsigned f2u16(_Float16 v) {
    return (unsigned)__builtin_bit_cast(unsigned short, v);
}

// LDS-ordered raw barrier: ds ops retired, then barrier; vmem stays in flight.
__device__ __forceinline__ void lds_barrier() {
    asm volatile("s_waitcnt lgkmcnt(0)" ::: "memory");
    __builtin_amdgcn_sched_barrier(0);
    __builtin_amdgcn_s_barrier();
}

// Wave-local ordering fence: ds writes retired before following ds reads issue.
__device__ __forceinline__ void lds_fence() {
    asm volatile("s_waitcnt lgkmcnt(0)" ::: "memory");
    __builtin_amdgcn_sched_barrier(0);
}

__global__ __launch_bounds__(NTHR, 2) void k_recur(const float* __restrict__ x,
                                                   const float* __restrict__ W,
                                                   const float* __restrict__ win,
                                                   float* __restrict__ out,
                                                   u32x4* __restrict__ hc) {
    __shared__ short hl16[4 * HROW];     // [4 b][1024 h + pad] f16
    __shared__ f32x4 part4[256];         // [8 wave][32 col] -> (b0..b3)
    unsigned int* hl32 = (unsigned int*)hl16;

    const int tid  = threadIdx.x;
    const int dom  = blockIdx.x & 7;
    const int wg   = blockIdx.x >> 3;
    const int c0   = wg * 32;
    const int b0   = dom * 4;
    const int lane = tid & 63;
    const int wv   = tid >> 6;          // wave owns h-cols [wv*128,+128) + x-cols [wv*32,+32)
    const int l15  = lane & 15;
    const int lg   = lane >> 4;         // 0..3

    // ---- one-time: W / W_in -> register B-fragments (f16) ----
    f16x8 bw[5][2];
#pragma unroll
    for (int kt = 0; kt < 4; ++kt)
#pragma unroll
        for (int ct = 0; ct < 2; ++ct)
#pragma unroll
            for (int j = 0; j < 8; ++j)
                bw[kt][ct][j] =
                    (_Float16)W[(size_t)(wv * 128 + kt * 32 + lg * 8 + j) * U_ + c0 + ct * 16 + l15];
#pragma unroll
    for (int ct = 0; ct < 2; ++ct)
#pragma unroll
        for (int j = 0; j < 8; ++j)
            bw[4][ct][j] =
                (_Float16)win[(size_t)(wv * 32 + lg * 8 + j) * U_ + c0 + ct * 16 + l15];

    // zero h region (h must be 0 at t=0)
    for (int i = tid; i < 2 * HROW; i += NTHR) hl32[i] = 0;
    __syncthreads();   // one-time, cold

    // A-frag base: row = batch (l15&3), k-group = lg
    const int ab = (l15 & 3) * HROW + lg * 8;
    // x source for this lane's kt=4 A-fragment: batch l15&3, cols wv*32 + lg*8 ..+8
    const float* xg = &x[((size_t)(b0 + (l15 & 3)) * T_) * D_ + wv * 32 + lg * 8];

    // prologue: x[t=0] into regs
    float4 xa = *(const float4*)xg;
    float4 xc = *(const float4*)(xg + 4);
    xg += D_;

    float hs0 = 0.f, hs1 = 0.f, hs2 = 0.f, hs3 = 0.f;   // tid<32 state

    for (int t = 0; t < T_; ++t) {
        u32x4 va, vb;
        if (t > 0) {
            // ---- poll own wave slice: 2 cols/thread, all 8 tags == t ----
            const u32x4* pp = hc + (size_t)((t & 1) * 8192 + dom * 1024 + 2 * tid);
            unsigned spin = 0;
            int ok;
            for (;;) {
                asm volatile(
                    "global_load_dwordx4 %0, %2, off sc1\n\t"
                    "global_load_dwordx4 %1, %2, off offset:16 sc1\n\t"
                    "s_waitcnt vmcnt(0)"
                    : "=&v"(va), "=&v"(vb)
                    : "v"(pp) : "memory");
                unsigned tg = (unsigned)t;
                ok = ((va[0] & 0xffffu) == tg) & ((va[1] & 0xffffu) == tg) &
                     ((va[2] & 0xffffu) == tg) & ((va[3] & 0xffffu) == tg) &
                     ((vb[0] & 0xffffu) == tg) & ((vb[1] & 0xffffu) == tg) &
                     ((vb[2] & 0xffffu) == tg) & ((vb[3] & 0xffffu) == tg);
                if (__all(ok) || ++spin > BAIL) break;
                __builtin_amdgcn_s_sleep(1);   // ~64 cyc: decongest the fabric
            }
            // ---- write polled h (cols 2*tid, 2*tid+1 per batch; wave-private) ----
#pragma unroll
            for (int b = 0; b < 4; ++b)
                hl32[b * (HROW / 2) + tid] = (va[b] >> 16) | (vb[b] & 0xffff0000u);
        }

        // ---- convert x[t] (loaded last iteration) to f16 ----
        f16x8 xf;
        xf[0] = (_Float16)xa.x; xf[1] = (_Float16)xa.y;
        xf[2] = (_Float16)xa.z; xf[3] = (_Float16)xa.w;
        xf[4] = (_Float16)xc.x; xf[5] = (_Float16)xc.y;
        xf[6] = (_Float16)xc.z; xf[7] = (_Float16)xc.w;

        lds_fence();   // wave-local: hl writes retired before A-frag reads (no barrier!)

        // ---- load x[t+1]: completion tracked at next iteration's use ----
        if (t + 1 < T_) {
            xa = *(const float4*)xg;
            xc = *(const float4*)(xg + 4);
            xg += D_;
        }

        // ---- MFMA: A = [h (own LDS slice) | x (regs)], B in regs, K=160 ----
        f32x4 acc0 = {0.f, 0.f, 0.f, 0.f}, acc1 = {0.f, 0.f, 0.f, 0.f};
#pragma unroll
        for (int kt = 0; kt < 4; ++kt) {
            f16x8 av = *reinterpret_cast<const f16x8*>(&hl16[ab + wv * 128 + kt * 32]);
            acc0 = __builtin_amdgcn_mfma_f32_16x16x32_f16(av, bw[kt][0], acc0, 0, 0, 0);
            acc1 = __builtin_amdgcn_mfma_f32_16x16x32_f16(av, bw[kt][1], acc1, 0, 0, 0);
        }
        acc0 = __builtin_amdgcn_mfma_f32_16x16x32_f16(xf, bw[4][0], acc0, 0, 0, 0);
        acc1 = __builtin_amdgcn_mfma_f32_16x16x32_f16(xf, bw[4][1], acc1, 0, 0, 0);

        if (lane < 16) {
            part4[wv * 32 + l15]      = acc0;
            part4[wv * 32 + 16 + l15] = acc1;
        }
        lds_barrier();   // (C) part4 writes retired (cross-wave)

        // ---- finalize + publish (lanes 0..31): atomic-store publish, then out ----
        if (tid < 32) {
            f32x4 s = part4[tid];
#pragma unroll
            for (int w2 = 1; w2 < 8; ++w2) s += part4[w2 * 32 + tid];
            float h0 = 0.8f * hs0 + 0.2f * tanh_fast(s[0]);
            float h1 = 0.8f * hs1 + 0.2f * tanh_fast(s[1]);
            float h2 = 0.8f * hs2 + 0.2f * tanh_fast(s[2]);
            float h3 = 0.8f * hs3 + 0.2f * tanh_fast(s[3]);
            hs0 = h0; hs1 = h1; hs2 = h2; hs3 = h3;
            unsigned tg = (unsigned)(t + 1) & 0xffffu;
            unsigned p0 = (f2u16((_Float16)h0) << 16) | tg;
            unsigned p1 = (f2u16((_Float16)h1) << 16) | tg;
            unsigned p2 = (f2u16((_Float16)h2) << 16) | tg;
            unsigned p3 = (f2u16((_Float16)h3) << 16) | tg;
            unsigned long long q0 = (unsigned long long)p0 | ((unsigned long long)p1 << 32);
            unsigned long long q1 = (unsigned long long)p2 | ((unsigned long long)p3 << 32);
            unsigned long long* dst = (unsigned long long*)
                (hc + (size_t)((((t + 1) & 1) * 8192) + dom * 1024 + c0 + tid));
            __hip_atomic_store(&dst[0], q0, __ATOMIC_RELAXED, __HIP_MEMORY_SCOPE_AGENT);
            __hip_atomic_store(&dst[1], q1, __ATOMIC_RELAXED, __HIP_MEMORY_SCOPE_AGENT);
            size_t ob = ((size_t)b0 * T_ + t) * U_ + c0 + tid;
            out[ob]                       = h0;
            out[ob + (size_t)T_ * U_]     = h1;
            out[ob + (size_t)2 * T_ * U_] = h2;
            out[ob + (size_t)3 * T_ * U_] = h3;
        }
        lds_barrier();   // (E) part4 reads retired; paces next poll (R10 lesson)
    }
}

extern "C" void kernel_launch(void* const* d_in, const int* in_sizes, int n_in,
                              void* d_out, int out_size, void* d_ws, size_t ws_size,
                              hipStream_t stream) {
    const float* x   = (const float*)d_in[0];   // [32,1024,256]
    const float* W   = (const float*)d_in[1];   // [1024,1024]
    const float* win = (const float*)d_in[2];   // [256,1024]
    float* out = (float*)d_out;                 // [32,1024,1024]

    // ws: hcast ring = 2 slots x 8 dom x 1024 cols x 16 B = 256 KB
    u32x4* hc = (u32x4*)d_ws;
    if (ws_size < 2 * 8 * 1024 * 16) return;

    hipMemsetAsync(d_ws, 0, 2 * 8 * 1024 * 16, stream);   // clean tags every call
    k_recur<<<dim3(256), dim3(NTHR), 0, stream>>>(x, W, win, out, hc);
}